// Round 23
// baseline (393.936 us; speedup 1.0000x reference)
//
#include <hip/hip_runtime.h>
#include <hip/hip_bf16.h>
#include <cstdint>
#include <cstddef>

#define H_DIM 1024
#define I_DIM 512
#define E_NUM 32
#define SHARED_I_DIM 1024
#define TOPK 4
#define NGROUP 8
#define TOPKG 4
#define GT 8   // tokens per gate block

typedef __attribute__((ext_vector_type(8))) short bf16x8;
typedef __attribute__((ext_vector_type(4))) float f32x4;
typedef __attribute__((ext_vector_type(8))) unsigned short u16x8;

__device__ inline unsigned short f2bf(float f) {
    __hip_bfloat16 h = __float2bfloat16(f);   // RNE -> v_cvt_pk_bf16_f32
    return *reinterpret_cast<unsigned short*>(&h);
}
__device__ inline float bf2f(unsigned short u) {
    union { unsigned int u; float f; } w;
    w.u = ((unsigned int)u) << 16;
    return w.f;
}

// LDS offset (shorts) for [rows][32] bf16 tile (64B rows), 16B chunks.
// Bank phase repeats every 2 rows -> swizzle on (row>>1); leaves only the
// free 2-way aliasing for 16-row fragment reads.
__device__ inline int laddr(int row, int chunk) {
    return row * 32 + ((chunk ^ ((row >> 1) & 3)) << 3);
}

// ---------------- gating: 8 tokens per block, fp32 exact ----------------
// Block 0 zeros cnt/cnt2; every block emits the bf16 copy of its rows.
__global__ __launch_bounds__(256) void gate_kernel(const float* __restrict__ x,
                                                   const float* __restrict__ gw,
                                                   float* __restrict__ logits_out,
                                                   unsigned short* __restrict__ x_bf,
                                                   int* __restrict__ cnt) {
    int tb = blockIdx.x;
    int tid = threadIdx.x;
    if (tb == 0 && tid < 64) cnt[tid] = 0;
    __shared__ float xs[GT][H_DIM];
    __shared__ float ps[8][GT][E_NUM];
    const float* xsrc = x + (size_t)tb * GT * H_DIM;
    for (int i = tid; i < GT * H_DIM / 4; i += 256)
        ((float4*)&xs[0][0])[i] = ((const float4*)xsrc)[i];
    __syncthreads();
    {
        unsigned short* dst = x_bf + (size_t)tb * GT * H_DIM;
#pragma unroll
        for (int i = 0; i < GT * H_DIM / 8 / 256; ++i) {
            int idx = i * 256 + tid;
            const float* s = &xs[0][0] + idx * 8;
            u16x8 v;
            v[0] = f2bf(s[0]); v[1] = f2bf(s[1]); v[2] = f2bf(s[2]); v[3] = f2bf(s[3]);
            v[4] = f2bf(s[4]); v[5] = f2bf(s[5]); v[6] = f2bf(s[6]); v[7] = f2bf(s[7]);
            *(u16x8*)(dst + idx * 8) = v;
        }
    }
    int e = tid & 31, part = tid >> 5;
    const float* wrow = gw + (size_t)e * H_DIM + part * 128;
    float acc[GT] = {};
    for (int c0 = 0; c0 < 128; c0 += 32) {
        float w[32];
#pragma unroll
        for (int c = 0; c < 32; c++) w[c] = wrow[c0 + c];
#pragma unroll
        for (int t = 0; t < GT; t++) {
#pragma unroll
            for (int c = 0; c < 32; c++)
                acc[t] += w[c] * xs[t][part * 128 + c0 + c];
        }
    }
#pragma unroll
    for (int t = 0; t < GT; t++) ps[part][t][e] = acc[t];
    __syncthreads();
    {
        int t = tid >> 5, ee = tid & 31;
        float s = 0.f;
#pragma unroll
        for (int p = 0; p < 8; p++) s += ps[p][t][ee];
        logits_out[((size_t)tb * GT + t) * E_NUM + ee] = s;
    }
}

// ---------------- selection ----------------
__global__ void select_kernel(const float* __restrict__ logits, const float* __restrict__ gb,
                              int* __restrict__ topk_e, float* __restrict__ topk_w,
                              int* __restrict__ cnt, int T) {
    int t = blockIdx.x * blockDim.x + threadIdx.x;
    if (t >= T) return;
    float scores[E_NUM], sfc[E_NUM];
#pragma unroll
    for (int i = 0; i < E_NUM; i++) {
        float l = logits[(size_t)t * E_NUM + i];
        float s = 1.f / (1.f + expf(-l));
        scores[i] = s;
        sfc[i] = s + gb[i];
    }
    float gs[NGROUP];
#pragma unroll
    for (int g = 0; g < NGROUP; g++) {
        float m1 = -1e30f, m2 = -1e30f;
#pragma unroll
        for (int j = 0; j < 4; j++) {
            float v = sfc[g * 4 + j];
            if (v > m1) { m2 = m1; m1 = v; }
            else if (v > m2) { m2 = v; }
        }
        gs[g] = m1 + m2;
    }
    unsigned gmask = 0;
    for (int r = 0; r < TOPKG; r++) {
        int best = 0; float bv = -1e30f;
#pragma unroll
        for (int g = 0; g < NGROUP; g++)
            if (!((gmask >> g) & 1u) && gs[g] > bv) { bv = gs[g]; best = g; }
        gmask |= 1u << best;
    }
    unsigned cmask = 0;
    int eidx[TOPK]; float ew[TOPK]; float sum = 0.f;
    for (int r = 0; r < TOPK; r++) {
        int best = 0; float bv = -1e30f; float bsc = 0.f;
#pragma unroll
        for (int i = 0; i < E_NUM; i++) {
            float v = ((gmask >> (i >> 2)) & 1u) ? sfc[i] : 0.0f;
            if (!((cmask >> i) & 1u) && v > bv) { bv = v; best = i; bsc = scores[i]; }
        }
        cmask |= 1u << best;
        eidx[r] = best; ew[r] = bsc; sum += bsc;
    }
    float inv = 1.f / (sum + 1e-20f);
#pragma unroll
    for (int k = 0; k < TOPK; k++) {
        topk_e[t * TOPK + k] = eidx[k];
        topk_w[t * TOPK + k] = ew[k] * inv;
        atomicAdd(&cnt[eidx[k]], 1);
    }
}

// ---------------- scan + tile-list build (BM=128) ----------------
// Compact lists of live tiles: contiguous live block ids pack evenly on CUs.
__global__ void scan_kernel(const int* __restrict__ cnt, int* __restrict__ off,
                            int* __restrict__ tiles1, int* __restrict__ tiles2,
                            int* __restrict__ nt, int T) {
    if (threadIdx.x != 0) return;
    int a = 0;
    for (int e = 0; e < E_NUM; e++) { off[e] = a; a += cnt[e]; }
    off[E_NUM] = a;
    int k1 = 0, k2 = 0;
    for (int e = 0; e < E_NUM; e++) {
        int nm = (cnt[e] + 127) >> 7;
        for (int mt = 0; mt < nm; mt++) {
            for (int it = 0; it < I_DIM / 64; it++)
                tiles1[k1++] = e | (it << 8) | (mt << 16);
            for (int it = 0; it < H_DIM / 64; it++)
                tiles2[k2++] = e | (it << 8) | (mt << 16);
        }
    }
    int nmsh = T >> 7;
    for (int mt = 0; mt < nmsh; mt++)
        for (int it = 0; it < 16; it++) {
            tiles1[k1++] = E_NUM | (it << 8) | (mt << 16);
            tiles2[k2++] = E_NUM | (it << 8) | (mt << 16);
        }
    nt[0] = k1;
    nt[1] = k2;
}

// ---------------- bin ----------------
__global__ void bin_kernel(const int* __restrict__ topk_e, const float* __restrict__ topk_w,
                           const int* __restrict__ off, int* __restrict__ cnt2,
                           int* __restrict__ slot_token, float* __restrict__ slot_w,
                           int* __restrict__ slot_of, int total) {
    int i = blockIdx.x * blockDim.x + threadIdx.x;
    if (i >= total) return;
    int e = topk_e[i];
    float w = topk_w[i];
    int pos = atomicAdd(&cnt2[e], 1);
    int slot = off[e] + pos;
    slot_token[slot] = i >> 2;
    slot_w[slot] = w;
    slot_of[i] = slot;
}

// ---------------- combine ----------------
__global__ __launch_bounds__(256) void combine_kernel(const unsigned short* __restrict__ out_slot,
                                                      const int* __restrict__ slot_of,
                                                      float* __restrict__ out) {
    int t = blockIdx.x;
    int h = threadIdx.x * 4;
    int s0 = slot_of[t * TOPK + 0], s1 = slot_of[t * TOPK + 1];
    int s2 = slot_of[t * TOPK + 2], s3 = slot_of[t * TOPK + 3];
    ushort4 a = *(const ushort4*)(out_slot + (size_t)s0 * H_DIM + h);
    ushort4 b = *(const ushort4*)(out_slot + (size_t)s1 * H_DIM + h);
    ushort4 c = *(const ushort4*)(out_slot + (size_t)s2 * H_DIM + h);
    ushort4 d = *(const ushort4*)(out_slot + (size_t)s3 * H_DIM + h);
    float4 o = *(float4*)(out + (size_t)t * H_DIM + h);
    o.x += bf2f(a.x) + bf2f(b.x) + bf2f(c.x) + bf2f(d.x);
    o.y += bf2f(a.y) + bf2f(b.y) + bf2f(c.y) + bf2f(d.y);
    o.z += bf2f(a.z) + bf2f(b.z) + bf2f(c.z) + bf2f(d.z);
    o.w += bf2f(a.w) + bf2f(b.w) + bf2f(c.w) + bf2f(d.w);
    *(float4*)(out + (size_t)t * H_DIM + h) = o;
}

// ------- merged MoE GEMM: 128x64 tile, BK=32, 256 thr, COMPACT GRID ----------
// 3 blocks/CU co-resident (LDS 32 KB dual / 24 KB single, VGPR ~80 @ (256,4)):
// three independent barrier chains per CU cover the per-step load latency
// that 2 chains could not (r22 step-time ~1400cyc vs ~400 compute).
// tile entry: e | itile<<8 | mtile<<16; e==E_NUM is the SHARED expert.
// 2-deep reg prefetch -> LDS dbuf -> __syncthreads; T5 setprio around MFMA.
// 4 waves: 2 wave-rows (64) x 2 wave-cols (32); MF=4, NF=2.
// STAGE1: act = silu(x@gateT)*(x@upT)*w -> bf16 (act_r routed / act_s shared)
// STAGE2: routed -> bf16 out_slot rows; shared -> fp32 out (once per (t,h))
template <bool STAGE1>
__global__ __launch_bounds__(256, 4) void moe_gemm(
    const unsigned short* __restrict__ Axr, const unsigned short* __restrict__ Axs,
    const float* __restrict__ B1r_, const float* __restrict__ B2r_,
    const float* __restrict__ B1s_, const float* __restrict__ B2s_,
    void* __restrict__ Dr, void* __restrict__ Ds,
    const int* __restrict__ slot_token, const float* __restrict__ slot_w,
    const int* __restrict__ cnt, const int* __restrict__ off_arr,
    const int* __restrict__ tiles, const int* __restrict__ nt, int T) {
    constexpr bool DUAL = STAGE1;
    int bid = blockIdx.x;
    if (bid >= nt[STAGE1 ? 0 : 1]) return;
    int tdesc = tiles[bid];
    int e = tdesc & 255, itile = (tdesc >> 8) & 255, mtile = tdesc >> 16;
    bool sh = (e == E_NUM);
    int count = sh ? T : cnt[e];
    int base = sh ? 0 : off_arr[e];
    const int K = STAGE1 ? H_DIM : (sh ? SHARED_I_DIM : I_DIM);

    __shared__ __align__(16) unsigned short As[2][128 * 32];    // 16 KB
    __shared__ __align__(16) unsigned short Bs1[2][64 * 32];    // 8 KB
    __shared__ __align__(16) unsigned short Bs2[2][DUAL ? 64 * 32 : 8];

    int tid = threadIdx.x, lane = tid & 63, wid = tid >> 6;

    // ---- A staging: 2 threads/row (128 rows), 2x16B chunks each ----
    int as_row = tid >> 1, as_c0 = (tid & 1) * 2;
    int am = mtile * 128 + as_row;
    int amc = (am < count) ? am : 0;
    const unsigned short* Abase;
    size_t arow;
    if constexpr (STAGE1) {
        Abase = Axr;
        arow = sh ? (size_t)amc : (size_t)slot_token[base + amc];
    } else {
        Abase = sh ? Axs : Axr;
        arow = sh ? (size_t)amc : (size_t)(base + amc);
    }
    const unsigned short* Ga = Abase + arow * K + as_c0 * 8;

    // ---- B staging: 4 threads/row (64 rows), 8 floats -> one 16B chunk ----
    int bs_row = tid >> 2, bs_ch = tid & 3;
    int brow = itile * 64 + bs_row;
    int bwr = laddr(bs_row, bs_ch);
    const float* Gb1;
    const float* Gb2 = nullptr;
    if constexpr (STAGE1) {
        Gb1 = (sh ? B1s_ : (B1r_ + (size_t)e * (I_DIM * H_DIM))) + (size_t)brow * K + bs_ch * 8;
        Gb2 = (sh ? B2s_ : (B2r_ + (size_t)e * (I_DIM * H_DIM))) + (size_t)brow * K + bs_ch * 8;
    } else {
        Gb1 = (sh ? B1s_ : (B1r_ + (size_t)e * (H_DIM * I_DIM))) + (size_t)brow * K + bs_ch * 8;
    }

    f32x4 acc1[4][2] = {};
    f32x4 acc2[DUAL ? 4 : 1][2] = {};

    int wrow = (wid >> 1) * 64, wcol = (wid & 1) * 32;
    int frow = lane & 15, fch = lane >> 4;

    // 2-deep prefetch sets (all statically indexed)
    u16x8 a00, a01, a10, a11;
    float4 b1lo0, b1hi0, b2lo0, b2hi0;
    float4 b1lo1, b1hi1, b2lo1, b2hi1;

    auto loadS = [&](u16x8& a0, u16x8& a1, float4& b1lo, float4& b1hi,
                     float4& b2lo, float4& b2hi, int ks) {
        int k0 = ks << 5;
        a0 = *(const u16x8*)(Ga + k0);
        a1 = *(const u16x8*)(Ga + k0 + 8);
        b1lo = *(const float4*)(Gb1 + k0);
        b1hi = *(const float4*)(Gb1 + k0 + 4);
        if constexpr (DUAL) {
            b2lo = *(const float4*)(Gb2 + k0);
            b2hi = *(const float4*)(Gb2 + k0 + 4);
        }
    };
    auto writeS = [&](int buf, u16x8 a0, u16x8 a1, float4 b1lo, float4 b1hi,
                      float4 b2lo, float4 b2hi) {
        *(u16x8*)(&As[buf][laddr(as_row, as_c0)]) = a0;
        *(u16x8*)(&As[buf][laddr(as_row, as_c0 + 1)]) = a1;
        u16x8 s;
        s[0] = f2bf(b1lo.x); s[1] = f2bf(b1lo.y); s[2] = f2bf(b1lo.z); s[3] = f2bf(b1lo.w);
        s[4] = f2bf(b1hi.x); s[5] = f2bf(b1hi.y); s[6] = f2bf(b1hi.z); s[7] = f2bf(b1hi.w);
        *(u16x8*)(&Bs1[buf][bwr]) = s;
        if constexpr (DUAL) {
            u16x8 s2;
            s2[0] = f2bf(b2lo.x); s2[1] = f2bf(b2lo.y); s2[2] = f2bf(b2lo.z); s2[3] = f2bf(b2lo.w);
            s2[4] = f2bf(b2hi.x); s2[5] = f2bf(b2hi.y); s2[6] = f2bf(b2hi.z); s2[7] = f2bf(b2hi.w);
            *(u16x8*)(&Bs2[buf][bwr]) = s2;
        }
    };
    auto compute = [&](int buf) {
        bf16x8 af[4], b1[2], b2[DUAL ? 2 : 1];
#pragma unroll
        for (int nf = 0; nf < 2; nf++)
            b1[nf] = *(const bf16x8*)(&Bs1[buf][laddr(wcol + nf * 16 + frow, fch)]);
        if constexpr (DUAL) {
#pragma unroll
            for (int nf = 0; nf < 2; nf++)
                b2[nf] = *(const bf16x8*)(&Bs2[buf][laddr(wcol + nf * 16 + frow, fch)]);
        }
#pragma unroll
        for (int mf = 0; mf < 4; mf++)
            af[mf] = *(const bf16x8*)(&As[buf][laddr(wrow + mf * 16 + frow, fch)]);
        __builtin_amdgcn_s_setprio(1);             // favor MFMA-phase waves
#pragma unroll
        for (int mf = 0; mf < 4; mf++)
#pragma unroll
            for (int nf = 0; nf < 2; nf++) {
                acc1[mf][nf] = __builtin_amdgcn_mfma_f32_16x16x32_bf16(af[mf], b1[nf], acc1[mf][nf], 0, 0, 0);
                if constexpr (DUAL)
                    acc2[mf][nf] = __builtin_amdgcn_mfma_f32_16x16x32_bf16(af[mf], b2[nf], acc2[mf][nf], 0, 0, 0);
            }
        __builtin_amdgcn_s_setprio(0);
    };

    const int NK = K >> 5;   // 32 or 16 (even)
    loadS(a00, a01, b1lo0, b1hi0, b2lo0, b2hi0, 0);
    loadS(a10, a11, b1lo1, b1hi1, b2lo1, b2hi1, 1);
    writeS(0, a00, a01, b1lo0, b1hi0, b2lo0, b2hi0);
    loadS(a00, a01, b1lo0, b1hi0, b2lo0, b2hi0, 2);
    __syncthreads();                               // buf0 ready
    for (int it = 0; it < NK; it += 2) {
        writeS(1, a10, a11, b1lo1, b1hi1, b2lo1, b2hi1);
        if (it + 3 < NK) loadS(a10, a11, b1lo1, b1hi1, b2lo1, b2hi1, it + 3);
        compute(0);
        __syncthreads();                           // buf1 ready, buf0 free
        if (it + 2 < NK) {
            writeS(0, a00, a01, b1lo0, b1hi0, b2lo0, b2hi0);
            if (it + 4 < NK) loadS(a00, a01, b1lo0, b1hi0, b2lo0, b2hi0, it + 4);
        }
        compute(1);
        if (it + 2 < NK) __syncthreads();          // buf0 ready, buf1 free
    }

    // ---- epilogue ----
#pragma unroll
    for (int mf = 0; mf < 4; mf++)
#pragma unroll
        for (int nf = 0; nf < 2; nf++)
#pragma unroll
            for (int j = 0; j < 4; j++) {
                int rloc = wrow + mf * 16 + (lane >> 4) * 4 + j;
                int mrow = mtile * 128 + rloc;
                int col = itile * 64 + wcol + nf * 16 + (lane & 15);
                if (mrow >= count) continue;
                if constexpr (STAGE1) {
                    float w = sh ? 1.0f : slot_w[base + mrow];
                    float g = acc1[mf][nf][j];
                    float a = (g / (1.f + __expf(-g))) * acc2[mf][nf][j] * w;
                    if (sh) ((unsigned short*)Ds)[(size_t)mrow * SHARED_I_DIM + col] = f2bf(a);
                    else    ((unsigned short*)Dr)[(size_t)(base + mrow) * I_DIM + col] = f2bf(a);
                } else {
                    if (sh) ((float*)Ds)[(size_t)mrow * H_DIM + col] = acc1[mf][nf][j];
                    else    ((unsigned short*)Dr)[(size_t)(base + mrow) * H_DIM + col] = f2bf(acc1[mf][nf][j]);
                }
            }
}

extern "C" void kernel_launch(void* const* d_in, const int* in_sizes, int n_in,
                              void* d_out, int out_size, void* d_ws, size_t ws_size,
                              hipStream_t stream) {
    const float* x = (const float*)d_in[0];
    const float* gw = (const float*)d_in[1];
    const float* gb = (const float*)d_in[2];
    const float* gate_proj = (const float*)d_in[3];
    const float* up_proj = (const float*)d_in[4];
    const float* down_proj = (const float*)d_in[5];
    const float* sgw = (const float*)d_in[6];
    const float* suw = (const float*)d_in[7];
    const float* sdw = (const float*)d_in[8];
    float* out = (float*)d_out;

    const int T = in_sizes[0] / H_DIM;       // 2048
    const int total_slots = T * TOPK;        // 8192

    char* ws = (char*)d_ws;
    int* cnt = (int*)ws;                     // 32
    int* cnt2 = cnt + 32;                    // 32
    int* off = cnt + 64;                     // 33
    int* nt = cnt + 100;                     // 2
    int* tiles1 = cnt + 128;                 // <= 1024
    int* tiles2 = tiles1 + 1024;             // <= 1792
    int* topk_e = tiles2 + 1792;
    float* topk_w = (float*)(topk_e + total_slots);
    int* slot_token = (int*)(topk_w + total_slots);
    float* slot_w = (float*)(slot_token + total_slots);
    int* slot_of = (int*)(slot_w + total_slots);
    float* logits = (float*)(slot_of + total_slots);              // T*32 f32
    unsigned short* x_bf = (unsigned short*)(logits + (size_t)T * E_NUM);
    unsigned short* act_r = x_bf + (size_t)T * H_DIM;             // (slots+128) x I
    unsigned short* act_s = act_r + (size_t)(total_slots + 128) * I_DIM;   // T x SHARED_I
    unsigned short* out_slot = act_s + (size_t)T * SHARED_I_DIM;  // (slots+128) x H

    // gate: logits + bf16 copy of x + zeroing of cnt/cnt2 (block 0)
    hipLaunchKernelGGL(gate_kernel, dim3(T / GT), dim3(256), 0, stream,
                       x, gw, logits, x_bf, cnt);
    hipLaunchKernelGGL(select_kernel, dim3((T + 255) / 256), dim3(256), 0, stream,
                       logits, gb, topk_e, topk_w, cnt, T);
    hipLaunchKernelGGL(scan_kernel, dim3(1), dim3(1), 0, stream,
                       cnt, off, tiles1, tiles2, nt, T);
    hipLaunchKernelGGL(bin_kernel, dim3((total_slots + 255) / 256), dim3(256), 0, stream,
                       topk_e, topk_w, off, cnt2, slot_token, slot_w, slot_of, total_slots);

    // stage 1 (compact 1-D grid; 768 live tiles = 3 blocks/CU)
    hipLaunchKernelGGL((moe_gemm<true>), dim3(1024), dim3(256), 0, stream,
                       x_bf, (const unsigned short*)nullptr,
                       gate_proj, up_proj, sgw, suw,
                       (void*)act_r, (void*)act_s,
                       slot_token, slot_w, cnt, off, tiles1, nt, T);

    // stage 2 (compact 1-D grid)
    hipLaunchKernelGGL((moe_gemm<false>), dim3(1792), dim3(256), 0, stream,
                       act_r, act_s,
                       down_proj, (const float*)nullptr, sdw, (const float*)nullptr,
                       (void*)out_slot, (void*)out,
                       slot_token, slot_w, cnt, off, tiles2, nt, T);

    // combine: out[t] += sum of the token's 4 routed slot rows
    hipLaunchKernelGGL(combine_kernel, dim3(T), dim3(256), 0, stream, out_slot, slot_of, out);
}

// Round 24
// 181.377 us; speedup vs baseline: 2.1719x; 2.1719x over previous
//
#include <hip/hip_runtime.h>
#include <hip/hip_bf16.h>
#include <cstdint>
#include <cstddef>

#define H_DIM 1024
#define I_DIM 512
#define E_NUM 32
#define SHARED_I_DIM 1024
#define TOPK 4
#define NGROUP 8
#define TOPKG 4
#define GT 8   // tokens per gate block

typedef __attribute__((ext_vector_type(8))) short bf16x8;
typedef __attribute__((ext_vector_type(4))) float f32x4;
typedef __attribute__((ext_vector_type(8))) unsigned short u16x8;

__device__ inline unsigned short f2bf(float f) {
    __hip_bfloat16 h = __float2bfloat16(f);   // RNE -> v_cvt_pk_bf16_f32
    return *reinterpret_cast<unsigned short*>(&h);
}
__device__ inline float bf2f(unsigned short u) {
    union { unsigned int u; float f; } w;
    w.u = ((unsigned int)u) << 16;
    return w.f;
}

// LDS offset (shorts) for [rows][32] bf16 tile (64B rows), 16B chunks.
// Bank phase repeats every 2 rows -> swizzle on (row>>1); leaves only the
// free 2-way aliasing for 16-row fragment reads.
__device__ inline int laddr(int row, int chunk) {
    return row * 32 + ((chunk ^ ((row >> 1) & 3)) << 3);
}

// ---------------- gating: 8 tokens per block, fp32 exact ----------------
// Block 0 zeros cnt/cnt2; every block emits the bf16 copy of its rows.
__global__ __launch_bounds__(256) void gate_kernel(const float* __restrict__ x,
                                                   const float* __restrict__ gw,
                                                   float* __restrict__ logits_out,
                                                   unsigned short* __restrict__ x_bf,
                                                   int* __restrict__ cnt) {
    int tb = blockIdx.x;
    int tid = threadIdx.x;
    if (tb == 0 && tid < 64) cnt[tid] = 0;
    __shared__ float xs[GT][H_DIM];
    __shared__ float ps[8][GT][E_NUM];
    const float* xsrc = x + (size_t)tb * GT * H_DIM;
    for (int i = tid; i < GT * H_DIM / 4; i += 256)
        ((float4*)&xs[0][0])[i] = ((const float4*)xsrc)[i];
    __syncthreads();
    {
        unsigned short* dst = x_bf + (size_t)tb * GT * H_DIM;
#pragma unroll
        for (int i = 0; i < GT * H_DIM / 8 / 256; ++i) {
            int idx = i * 256 + tid;
            const float* s = &xs[0][0] + idx * 8;
            u16x8 v;
            v[0] = f2bf(s[0]); v[1] = f2bf(s[1]); v[2] = f2bf(s[2]); v[3] = f2bf(s[3]);
            v[4] = f2bf(s[4]); v[5] = f2bf(s[5]); v[6] = f2bf(s[6]); v[7] = f2bf(s[7]);
            *(u16x8*)(dst + idx * 8) = v;
        }
    }
    int e = tid & 31, part = tid >> 5;
    const float* wrow = gw + (size_t)e * H_DIM + part * 128;
    float acc[GT] = {};
    for (int c0 = 0; c0 < 128; c0 += 32) {
        float w[32];
#pragma unroll
        for (int c = 0; c < 32; c++) w[c] = wrow[c0 + c];
#pragma unroll
        for (int t = 0; t < GT; t++) {
#pragma unroll
            for (int c = 0; c < 32; c++)
                acc[t] += w[c] * xs[t][part * 128 + c0 + c];
        }
    }
#pragma unroll
    for (int t = 0; t < GT; t++) ps[part][t][e] = acc[t];
    __syncthreads();
    {
        int t = tid >> 5, ee = tid & 31;
        float s = 0.f;
#pragma unroll
        for (int p = 0; p < 8; p++) s += ps[p][t][ee];
        logits_out[((size_t)tb * GT + t) * E_NUM + ee] = s;
    }
}

// ---------------- selection ----------------
__global__ void select_kernel(const float* __restrict__ logits, const float* __restrict__ gb,
                              int* __restrict__ topk_e, float* __restrict__ topk_w,
                              int* __restrict__ cnt, int T) {
    int t = blockIdx.x * blockDim.x + threadIdx.x;
    if (t >= T) return;
    float scores[E_NUM], sfc[E_NUM];
#pragma unroll
    for (int i = 0; i < E_NUM; i++) {
        float l = logits[(size_t)t * E_NUM + i];
        float s = 1.f / (1.f + expf(-l));
        scores[i] = s;
        sfc[i] = s + gb[i];
    }
    float gs[NGROUP];
#pragma unroll
    for (int g = 0; g < NGROUP; g++) {
        float m1 = -1e30f, m2 = -1e30f;
#pragma unroll
        for (int j = 0; j < 4; j++) {
            float v = sfc[g * 4 + j];
            if (v > m1) { m2 = m1; m1 = v; }
            else if (v > m2) { m2 = v; }
        }
        gs[g] = m1 + m2;
    }
    unsigned gmask = 0;
    for (int r = 0; r < TOPKG; r++) {
        int best = 0; float bv = -1e30f;
#pragma unroll
        for (int g = 0; g < NGROUP; g++)
            if (!((gmask >> g) & 1u) && gs[g] > bv) { bv = gs[g]; best = g; }
        gmask |= 1u << best;
    }
    unsigned cmask = 0;
    int eidx[TOPK]; float ew[TOPK]; float sum = 0.f;
    for (int r = 0; r < TOPK; r++) {
        int best = 0; float bv = -1e30f; float bsc = 0.f;
#pragma unroll
        for (int i = 0; i < E_NUM; i++) {
            float v = ((gmask >> (i >> 2)) & 1u) ? sfc[i] : 0.0f;
            if (!((cmask >> i) & 1u) && v > bv) { bv = v; best = i; bsc = scores[i]; }
        }
        cmask |= 1u << best;
        eidx[r] = best; ew[r] = bsc; sum += bsc;
    }
    float inv = 1.f / (sum + 1e-20f);
#pragma unroll
    for (int k = 0; k < TOPK; k++) {
        topk_e[t * TOPK + k] = eidx[k];
        topk_w[t * TOPK + k] = ew[k] * inv;
        atomicAdd(&cnt[eidx[k]], 1);
    }
}

// ---------------- scan + tile-list build ----------------
// Compact lists of live tiles so GEMM grids have CONTIGUOUS live block ids
// (round-robin dispatch then packs them evenly over CUs).
__global__ void scan_kernel(const int* __restrict__ cnt, int* __restrict__ off,
                            int* __restrict__ tiles1, int* __restrict__ tiles2,
                            int* __restrict__ nt, int T) {
    if (threadIdx.x != 0) return;
    int a = 0;
    for (int e = 0; e < E_NUM; e++) { off[e] = a; a += cnt[e]; }
    off[E_NUM] = a;
    int k1 = 0, k2 = 0;
    for (int e = 0; e < E_NUM; e++) {
        int nm = (cnt[e] + 255) >> 8;
        for (int mt = 0; mt < nm; mt++) {
            for (int it = 0; it < I_DIM / 64; it++)
                tiles1[k1++] = e | (it << 8) | (mt << 16);
            for (int it = 0; it < H_DIM / 64; it++)
                tiles2[k2++] = e | (it << 8) | (mt << 16);
        }
    }
    int nmsh = T >> 8;
    for (int mt = 0; mt < nmsh; mt++)
        for (int it = 0; it < 16; it++) {
            tiles1[k1++] = E_NUM | (it << 8) | (mt << 16);
            tiles2[k2++] = E_NUM | (it << 8) | (mt << 16);
        }
    nt[0] = k1;
    nt[1] = k2;
}

// ---------------- bin ----------------
__global__ void bin_kernel(const int* __restrict__ topk_e, const float* __restrict__ topk_w,
                           const int* __restrict__ off, int* __restrict__ cnt2,
                           int* __restrict__ slot_token, float* __restrict__ slot_w,
                           int* __restrict__ slot_of, int total) {
    int i = blockIdx.x * blockDim.x + threadIdx.x;
    if (i >= total) return;
    int e = topk_e[i];
    float w = topk_w[i];
    int pos = atomicAdd(&cnt2[e], 1);
    int slot = off[e] + pos;
    slot_token[slot] = i >> 2;
    slot_w[slot] = w;
    slot_of[i] = slot;
}

// ---------------- combine ----------------
__global__ __launch_bounds__(256) void combine_kernel(const unsigned short* __restrict__ out_slot,
                                                      const int* __restrict__ slot_of,
                                                      float* __restrict__ out) {
    int t = blockIdx.x;
    int h = threadIdx.x * 4;
    int s0 = slot_of[t * TOPK + 0], s1 = slot_of[t * TOPK + 1];
    int s2 = slot_of[t * TOPK + 2], s3 = slot_of[t * TOPK + 3];
    ushort4 a = *(const ushort4*)(out_slot + (size_t)s0 * H_DIM + h);
    ushort4 b = *(const ushort4*)(out_slot + (size_t)s1 * H_DIM + h);
    ushort4 c = *(const ushort4*)(out_slot + (size_t)s2 * H_DIM + h);
    ushort4 d = *(const ushort4*)(out_slot + (size_t)s3 * H_DIM + h);
    float4 o = *(float4*)(out + (size_t)t * H_DIM + h);
    o.x += bf2f(a.x) + bf2f(b.x) + bf2f(c.x) + bf2f(d.x);
    o.y += bf2f(a.y) + bf2f(b.y) + bf2f(c.y) + bf2f(d.y);
    o.z += bf2f(a.z) + bf2f(b.z) + bf2f(c.z) + bf2f(d.z);
    o.w += bf2f(a.w) + bf2f(b.w) + bf2f(c.w) + bf2f(d.w);
    *(float4*)(out + (size_t)t * H_DIM + h) = o;
}

// ------- merged MoE GEMM: 256x64 tile, BK=32, 512 thr, COMPACT 1-D GRID ------
// tile list entry: e | itile<<8 | mtile<<16; e==E_NUM is the SHARED expert.
// 2-deep reg prefetch -> LDS dbuf -> __syncthreads; T5 setprio around MFMA.
// launch_bounds MUST stay (512,2): VGPR cap 128 (measured 76, no spills);
// tighter caps (r7/r23) forced VGPR<=64 -> hundreds of MB of scratch.
// 8 waves: 4 wave-rows (64) x 2 wave-cols (32); MF=4, NF=2.
// STAGE1: act = silu(x@gateT)*(x@upT)*w -> bf16 (act_r routed / act_s shared)
// STAGE2: routed -> bf16 out_slot rows; shared -> fp32 out (once per (t,h))
template <bool STAGE1>
__global__ __launch_bounds__(512, 2) void moe_gemm(
    const unsigned short* __restrict__ Axr, const unsigned short* __restrict__ Axs,
    const float* __restrict__ B1r_, const float* __restrict__ B2r_,
    const float* __restrict__ B1s_, const float* __restrict__ B2s_,
    void* __restrict__ Dr, void* __restrict__ Ds,
    const int* __restrict__ slot_token, const float* __restrict__ slot_w,
    const int* __restrict__ cnt, const int* __restrict__ off_arr,
    const int* __restrict__ tiles, const int* __restrict__ nt, int T) {
    constexpr bool DUAL = STAGE1;
    int bid = blockIdx.x;
    if (bid >= nt[STAGE1 ? 0 : 1]) return;
    int tdesc = tiles[bid];
    int e = tdesc & 255, itile = (tdesc >> 8) & 255, mtile = tdesc >> 16;
    bool sh = (e == E_NUM);
    int count = sh ? T : cnt[e];
    int base = sh ? 0 : off_arr[e];
    const int K = STAGE1 ? H_DIM : (sh ? SHARED_I_DIM : I_DIM);

    __shared__ __align__(16) unsigned short As[2][256 * 32];    // 32 KB
    __shared__ __align__(16) unsigned short Bs1[2][64 * 32];    // 8 KB
    __shared__ __align__(16) unsigned short Bs2[2][DUAL ? 64 * 32 : 8];

    int tid = threadIdx.x, lane = tid & 63, wid = tid >> 6;

    // ---- A staging: 2 threads/row, 2x16B chunks each ----
    int as_row = tid >> 1, as_c0 = (tid & 1) * 2;
    int am = mtile * 256 + as_row;
    int amc = (am < count) ? am : 0;
    const unsigned short* Abase;
    size_t arow;
    if constexpr (STAGE1) {
        Abase = Axr;
        arow = sh ? (size_t)amc : (size_t)slot_token[base + amc];
    } else {
        Abase = sh ? Axs : Axr;
        arow = sh ? (size_t)amc : (size_t)(base + amc);
    }
    const unsigned short* Ga = Abase + arow * K + as_c0 * 8;

    // ---- B staging: 8 threads/row, 4 floats each -> 8B bf16 ds_write ----
    int bs_row = tid >> 3;
    int brow = itile * 64 + bs_row;
    int bwr = laddr(bs_row, (tid & 7) >> 1) + (tid & 1) * 4;
    const float* Gb1;
    const float* Gb2 = nullptr;
    if constexpr (STAGE1) {
        Gb1 = (sh ? B1s_ : (B1r_ + (size_t)e * (I_DIM * H_DIM))) + (size_t)brow * K + (tid & 7) * 4;
        Gb2 = (sh ? B2s_ : (B2r_ + (size_t)e * (I_DIM * H_DIM))) + (size_t)brow * K + (tid & 7) * 4;
    } else {
        Gb1 = (sh ? B1s_ : (B1r_ + (size_t)e * (H_DIM * I_DIM))) + (size_t)brow * K + (tid & 7) * 4;
    }

    f32x4 acc1[4][2] = {};
    f32x4 acc2[DUAL ? 4 : 1][2] = {};

    int wrow = (wid >> 1) * 64, wcol = (wid & 1) * 32;
    int frow = lane & 15, fch = lane >> 4;

    // 2-deep prefetch sets (all statically indexed)
    u16x8 a00, a01, a10, a11;
    float4 b10, b20, b11, b21;

    auto loadS = [&](u16x8& a0, u16x8& a1, float4& b1v, float4& b2v, int ks) {
        int k0 = ks << 5;
        a0 = *(const u16x8*)(Ga + k0);
        a1 = *(const u16x8*)(Ga + k0 + 8);
        b1v = *(const float4*)(Gb1 + k0);
        if constexpr (DUAL) b2v = *(const float4*)(Gb2 + k0);
    };
    auto writeS = [&](int buf, u16x8 a0, u16x8 a1, float4 b1v, float4 b2v) {
        *(u16x8*)(&As[buf][laddr(as_row, as_c0)]) = a0;
        *(u16x8*)(&As[buf][laddr(as_row, as_c0 + 1)]) = a1;
        ushort4 s;
        s.x = f2bf(b1v.x); s.y = f2bf(b1v.y); s.z = f2bf(b1v.z); s.w = f2bf(b1v.w);
        *(ushort4*)(&Bs1[buf][bwr]) = s;
        if constexpr (DUAL) {
            ushort4 s2;
            s2.x = f2bf(b2v.x); s2.y = f2bf(b2v.y); s2.z = f2bf(b2v.z); s2.w = f2bf(b2v.w);
            *(ushort4*)(&Bs2[buf][bwr]) = s2;
        }
    };
    auto compute = [&](int buf) {
        bf16x8 af[4], b1[2], b2[DUAL ? 2 : 1];
#pragma unroll
        for (int nf = 0; nf < 2; nf++)
            b1[nf] = *(const bf16x8*)(&Bs1[buf][laddr(wcol + nf * 16 + frow, fch)]);
        if constexpr (DUAL) {
#pragma unroll
            for (int nf = 0; nf < 2; nf++)
                b2[nf] = *(const bf16x8*)(&Bs2[buf][laddr(wcol + nf * 16 + frow, fch)]);
        }
#pragma unroll
        for (int mf = 0; mf < 4; mf++)
            af[mf] = *(const bf16x8*)(&As[buf][laddr(wrow + mf * 16 + frow, fch)]);
        __builtin_amdgcn_s_setprio(1);             // favor MFMA-phase waves
#pragma unroll
        for (int mf = 0; mf < 4; mf++)
#pragma unroll
            for (int nf = 0; nf < 2; nf++) {
                acc1[mf][nf] = __builtin_amdgcn_mfma_f32_16x16x32_bf16(af[mf], b1[nf], acc1[mf][nf], 0, 0, 0);
                if constexpr (DUAL)
                    acc2[mf][nf] = __builtin_amdgcn_mfma_f32_16x16x32_bf16(af[mf], b2[nf], acc2[mf][nf], 0, 0, 0);
            }
        __builtin_amdgcn_s_setprio(0);
    };

    const int NK = K >> 5;   // 32 or 16 (even)
    loadS(a00, a01, b10, b20, 0);
    loadS(a10, a11, b11, b21, 1);
    writeS(0, a00, a01, b10, b20);
    loadS(a00, a01, b10, b20, 2);
    __syncthreads();                               // buf0 ready
    for (int it = 0; it < NK; it += 2) {
        writeS(1, a10, a11, b11, b21);
        if (it + 3 < NK) loadS(a10, a11, b11, b21, it + 3);
        compute(0);
        __syncthreads();                           // buf1 ready, buf0 free
        if (it + 2 < NK) {
            writeS(0, a00, a01, b10, b20);
            if (it + 4 < NK) loadS(a00, a01, b10, b20, it + 4);
        }
        compute(1);
        if (it + 2 < NK) __syncthreads();          // buf0 ready, buf1 free
    }

    // ---- epilogue ----
#pragma unroll
    for (int mf = 0; mf < 4; mf++)
#pragma unroll
        for (int nf = 0; nf < 2; nf++)
#pragma unroll
            for (int j = 0; j < 4; j++) {
                int rloc = wrow + mf * 16 + (lane >> 4) * 4 + j;
                int mrow = mtile * 256 + rloc;
                int col = itile * 64 + wcol + nf * 16 + (lane & 15);
                if (mrow >= count) continue;
                if constexpr (STAGE1) {
                    float w = sh ? 1.0f : slot_w[base + mrow];
                    float g = acc1[mf][nf][j];
                    float a = (g / (1.f + __expf(-g))) * acc2[mf][nf][j] * w;
                    if (sh) ((unsigned short*)Ds)[(size_t)mrow * SHARED_I_DIM + col] = f2bf(a);
                    else    ((unsigned short*)Dr)[(size_t)(base + mrow) * I_DIM + col] = f2bf(a);
                } else {
                    if (sh) ((float*)Ds)[(size_t)mrow * H_DIM + col] = acc1[mf][nf][j];
                    else    ((unsigned short*)Dr)[(size_t)(base + mrow) * H_DIM + col] = f2bf(acc1[mf][nf][j]);
                }
            }
}

extern "C" void kernel_launch(void* const* d_in, const int* in_sizes, int n_in,
                              void* d_out, int out_size, void* d_ws, size_t ws_size,
                              hipStream_t stream) {
    const float* x = (const float*)d_in[0];
    const float* gw = (const float*)d_in[1];
    const float* gb = (const float*)d_in[2];
    const float* gate_proj = (const float*)d_in[3];
    const float* up_proj = (const float*)d_in[4];
    const float* down_proj = (const float*)d_in[5];
    const float* sgw = (const float*)d_in[6];
    const float* suw = (const float*)d_in[7];
    const float* sdw = (const float*)d_in[8];
    float* out = (float*)d_out;

    const int T = in_sizes[0] / H_DIM;       // 2048
    const int total_slots = T * TOPK;        // 8192

    char* ws = (char*)d_ws;
    int* cnt = (int*)ws;                     // 32
    int* cnt2 = cnt + 32;                    // 32
    int* off = cnt + 64;                     // 33
    int* nt = cnt + 100;                     // 2
    int* tiles1 = cnt + 128;                 // <= 768
    int* tiles2 = tiles1 + 768;              // <= 1280
    int* topk_e = tiles2 + 1280;
    float* topk_w = (float*)(topk_e + total_slots);
    int* slot_token = (int*)(topk_w + total_slots);
    float* slot_w = (float*)(slot_token + total_slots);
    int* slot_of = (int*)(slot_w + total_slots);
    float* logits = (float*)(slot_of + total_slots);              // T*32 f32
    unsigned short* x_bf = (unsigned short*)(logits + (size_t)T * E_NUM);
    unsigned short* act_r = x_bf + (size_t)T * H_DIM;             // (slots+256) x I
    unsigned short* act_s = act_r + (size_t)(total_slots + 256) * I_DIM;   // T x SHARED_I
    unsigned short* out_slot = act_s + (size_t)T * SHARED_I_DIM;  // (slots+256) x H

    // gate: logits + bf16 copy of x + zeroing of cnt/cnt2 (block 0)
    hipLaunchKernelGGL(gate_kernel, dim3(T / GT), dim3(256), 0, stream,
                       x, gw, logits, x_bf, cnt);
    hipLaunchKernelGGL(select_kernel, dim3((T + 255) / 256), dim3(256), 0, stream,
                       logits, gb, topk_e, topk_w, cnt, T);
    hipLaunchKernelGGL(scan_kernel, dim3(1), dim3(1), 0, stream,
                       cnt, off, tiles1, tiles2, nt, T);
    hipLaunchKernelGGL(bin_kernel, dim3((total_slots + 255) / 256), dim3(256), 0, stream,
                       topk_e, topk_w, off, cnt2, slot_token, slot_w, slot_of, total_slots);

    // stage 1 (compact 1-D grid; live tiles contiguous from block 0)
    hipLaunchKernelGGL((moe_gemm<true>), dim3(768), dim3(512), 0, stream,
                       x_bf, (const unsigned short*)nullptr,
                       gate_proj, up_proj, sgw, suw,
                       (void*)act_r, (void*)act_s,
                       slot_token, slot_w, cnt, off, tiles1, nt, T);

    // stage 2 (compact 1-D grid)
    hipLaunchKernelGGL((moe_gemm<false>), dim3(1280), dim3(512), 0, stream,
                       act_r, act_s,
                       down_proj, (const float*)nullptr, sdw, (const float*)nullptr,
                       (void*)out_slot, (void*)out,
                       slot_token, slot_w, cnt, off, tiles2, nt, T);

    // combine: out[t] += sum of the token's 4 routed slot rows
    hipLaunchKernelGGL(combine_kernel, dim3(T), dim3(256), 0, stream, out_slot, slot_of, out);
}

// Round 25
// 173.617 us; speedup vs baseline: 2.2690x; 1.0447x over previous
//
#include <hip/hip_runtime.h>
#include <hip/hip_bf16.h>
#include <cstdint>
#include <cstddef>

#define H_DIM 1024
#define I_DIM 512
#define E_NUM 32
#define SHARED_I_DIM 1024
#define TOPK 4
#define NGROUP 8
#define TOPKG 4
#define GT 8   // tokens per gate block

typedef __attribute__((ext_vector_type(8))) short bf16x8;
typedef __attribute__((ext_vector_type(4))) float f32x4;
typedef __attribute__((ext_vector_type(8))) unsigned short u16x8;

__device__ inline unsigned short f2bf(float f) {
    __hip_bfloat16 h = __float2bfloat16(f);   // RNE -> v_cvt_pk_bf16_f32
    return *reinterpret_cast<unsigned short*>(&h);
}
__device__ inline float bf2f(unsigned short u) {
    union { unsigned int u; float f; } w;
    w.u = ((unsigned int)u) << 16;
    return w.f;
}

// LDS offset (shorts) for [rows][32] bf16 tile (64B rows), 16B chunks.
// Bank phase repeats every 2 rows -> swizzle on (row>>1); leaves only the
// free 2-way aliasing for 16-row fragment reads.
__device__ inline int laddr(int row, int chunk) {
    return row * 32 + ((chunk ^ ((row >> 1) & 3)) << 3);
}

// ---------------- gating: 8 tokens per block, fp32 exact ----------------
// Block 0 zeros cnt/cnt2; every block emits the bf16 copy of its rows.
__global__ __launch_bounds__(256) void gate_kernel(const float* __restrict__ x,
                                                   const float* __restrict__ gw,
                                                   float* __restrict__ logits_out,
                                                   unsigned short* __restrict__ x_bf,
                                                   int* __restrict__ cnt) {
    int tb = blockIdx.x;
    int tid = threadIdx.x;
    if (tb == 0 && tid < 64) cnt[tid] = 0;
    __shared__ float xs[GT][H_DIM];
    __shared__ float ps[8][GT][E_NUM];
    const float* xsrc = x + (size_t)tb * GT * H_DIM;
    for (int i = tid; i < GT * H_DIM / 4; i += 256)
        ((float4*)&xs[0][0])[i] = ((const float4*)xsrc)[i];
    __syncthreads();
    {
        unsigned short* dst = x_bf + (size_t)tb * GT * H_DIM;
#pragma unroll
        for (int i = 0; i < GT * H_DIM / 8 / 256; ++i) {
            int idx = i * 256 + tid;
            const float* s = &xs[0][0] + idx * 8;
            u16x8 v;
            v[0] = f2bf(s[0]); v[1] = f2bf(s[1]); v[2] = f2bf(s[2]); v[3] = f2bf(s[3]);
            v[4] = f2bf(s[4]); v[5] = f2bf(s[5]); v[6] = f2bf(s[6]); v[7] = f2bf(s[7]);
            *(u16x8*)(dst + idx * 8) = v;
        }
    }
    int e = tid & 31, part = tid >> 5;
    const float* wrow = gw + (size_t)e * H_DIM + part * 128;
    float acc[GT] = {};
    for (int c0 = 0; c0 < 128; c0 += 32) {
        float w[32];
#pragma unroll
        for (int c = 0; c < 32; c++) w[c] = wrow[c0 + c];
#pragma unroll
        for (int t = 0; t < GT; t++) {
#pragma unroll
            for (int c = 0; c < 32; c++)
                acc[t] += w[c] * xs[t][part * 128 + c0 + c];
        }
    }
#pragma unroll
    for (int t = 0; t < GT; t++) ps[part][t][e] = acc[t];
    __syncthreads();
    {
        int t = tid >> 5, ee = tid & 31;
        float s = 0.f;
#pragma unroll
        for (int p = 0; p < 8; p++) s += ps[p][t][ee];
        logits_out[((size_t)tb * GT + t) * E_NUM + ee] = s;
    }
}

// ---------------- selection ----------------
__global__ void select_kernel(const float* __restrict__ logits, const float* __restrict__ gb,
                              int* __restrict__ topk_e, float* __restrict__ topk_w,
                              int* __restrict__ cnt, int T) {
    int t = blockIdx.x * blockDim.x + threadIdx.x;
    if (t >= T) return;
    float scores[E_NUM], sfc[E_NUM];
#pragma unroll
    for (int i = 0; i < E_NUM; i++) {
        float l = logits[(size_t)t * E_NUM + i];
        float s = 1.f / (1.f + expf(-l));
        scores[i] = s;
        sfc[i] = s + gb[i];
    }
    float gs[NGROUP];
#pragma unroll
    for (int g = 0; g < NGROUP; g++) {
        float m1 = -1e30f, m2 = -1e30f;
#pragma unroll
        for (int j = 0; j < 4; j++) {
            float v = sfc[g * 4 + j];
            if (v > m1) { m2 = m1; m1 = v; }
            else if (v > m2) { m2 = v; }
        }
        gs[g] = m1 + m2;
    }
    unsigned gmask = 0;
    for (int r = 0; r < TOPKG; r++) {
        int best = 0; float bv = -1e30f;
#pragma unroll
        for (int g = 0; g < NGROUP; g++)
            if (!((gmask >> g) & 1u) && gs[g] > bv) { bv = gs[g]; best = g; }
        gmask |= 1u << best;
    }
    unsigned cmask = 0;
    int eidx[TOPK]; float ew[TOPK]; float sum = 0.f;
    for (int r = 0; r < TOPK; r++) {
        int best = 0; float bv = -1e30f; float bsc = 0.f;
#pragma unroll
        for (int i = 0; i < E_NUM; i++) {
            float v = ((gmask >> (i >> 2)) & 1u) ? sfc[i] : 0.0f;
            if (!((cmask >> i) & 1u) && v > bv) { bv = v; best = i; bsc = scores[i]; }
        }
        cmask |= 1u << best;
        eidx[r] = best; ew[r] = bsc; sum += bsc;
    }
    float inv = 1.f / (sum + 1e-20f);
#pragma unroll
    for (int k = 0; k < TOPK; k++) {
        topk_e[t * TOPK + k] = eidx[k];
        topk_w[t * TOPK + k] = ew[k] * inv;
        atomicAdd(&cnt[eidx[k]], 1);
    }
}

// ---------------- scan + PARALLEL tile-list build ----------------
// Thread 0 does only the 32-entry prefix sums (into LDS); the tile-list
// fill is strided-parallel over 256 threads (the old 1-thread serial fill
// of ~1800 entries was ~5-10us of pure latency on the critical path).
__global__ __launch_bounds__(256) void scan_kernel(const int* __restrict__ cnt,
                                                   int* __restrict__ off,
                                                   int* __restrict__ tiles1,
                                                   int* __restrict__ tiles2,
                                                   int* __restrict__ nt, int T) {
    __shared__ int s_nm[E_NUM];
    __shared__ int s_t1[E_NUM + 1];
    __shared__ int s_t2[E_NUM + 1];
    int tid = threadIdx.x;
    if (tid == 0) {
        int a = 0, k1 = 0, k2 = 0;
        for (int e = 0; e < E_NUM; e++) {
            off[e] = a; a += cnt[e];
            int nm = (cnt[e] + 255) >> 8;
            s_nm[e] = nm;
            s_t1[e] = k1; k1 += nm * (I_DIM / 64);
            s_t2[e] = k2; k2 += nm * (H_DIM / 64);
        }
        off[E_NUM] = a;
        s_t1[E_NUM] = k1;
        s_t2[E_NUM] = k2;
        int nmsh = T >> 8;
        nt[0] = k1 + nmsh * 16;
        nt[1] = k2 + nmsh * 16;
    }
    __syncthreads();
    for (int e = 0; e < E_NUM; e++) {
        int nm = s_nm[e];
        for (int i = tid; i < nm * 8; i += 256) {
            int mt = i >> 3, it = i & 7;
            tiles1[s_t1[e] + i] = e | (it << 8) | (mt << 16);
        }
        for (int i = tid; i < nm * 16; i += 256) {
            int mt = i >> 4, it = i & 15;
            tiles2[s_t2[e] + i] = e | (it << 8) | (mt << 16);
        }
    }
    int nsh = (T >> 8) * 16;
    for (int i = tid; i < nsh; i += 256) {
        int mt = i >> 4, it = i & 15;
        tiles1[s_t1[E_NUM] + i] = E_NUM | (it << 8) | (mt << 16);
        tiles2[s_t2[E_NUM] + i] = E_NUM | (it << 8) | (mt << 16);
    }
}

// ---------------- bin ----------------
__global__ void bin_kernel(const int* __restrict__ topk_e, const float* __restrict__ topk_w,
                           const int* __restrict__ off, int* __restrict__ cnt2,
                           int* __restrict__ slot_token, float* __restrict__ slot_w,
                           int* __restrict__ slot_of, int total) {
    int i = blockIdx.x * blockDim.x + threadIdx.x;
    if (i >= total) return;
    int e = topk_e[i];
    float w = topk_w[i];
    int pos = atomicAdd(&cnt2[e], 1);
    int slot = off[e] + pos;
    slot_token[slot] = i >> 2;
    slot_w[slot] = w;
    slot_of[i] = slot;
}

// ---------------- combine ----------------
__global__ __launch_bounds__(256) void combine_kernel(const unsigned short* __restrict__ out_slot,
                                                      const int* __restrict__ slot_of,
                                                      float* __restrict__ out) {
    int t = blockIdx.x;
    int h = threadIdx.x * 4;
    int s0 = slot_of[t * TOPK + 0], s1 = slot_of[t * TOPK + 1];
    int s2 = slot_of[t * TOPK + 2], s3 = slot_of[t * TOPK + 3];
    ushort4 a = *(const ushort4*)(out_slot + (size_t)s0 * H_DIM + h);
    ushort4 b = *(const ushort4*)(out_slot + (size_t)s1 * H_DIM + h);
    ushort4 c = *(const ushort4*)(out_slot + (size_t)s2 * H_DIM + h);
    ushort4 d = *(const ushort4*)(out_slot + (size_t)s3 * H_DIM + h);
    float4 o = *(float4*)(out + (size_t)t * H_DIM + h);
    o.x += bf2f(a.x) + bf2f(b.x) + bf2f(c.x) + bf2f(d.x);
    o.y += bf2f(a.y) + bf2f(b.y) + bf2f(c.y) + bf2f(d.y);
    o.z += bf2f(a.z) + bf2f(b.z) + bf2f(c.z) + bf2f(d.z);
    o.w += bf2f(a.w) + bf2f(b.w) + bf2f(c.w) + bf2f(d.w);
    *(float4*)(out + (size_t)t * H_DIM + h) = o;
}

// ------- merged MoE GEMM: 256x64 tile, BK=32, 512 thr, COMPACT 1-D GRID ------
// tile list entry: e | itile<<8 | mtile<<16; e==E_NUM is the SHARED expert.
// 2-deep reg prefetch -> LDS dbuf -> __syncthreads; T5 setprio around MFMA.
// launch_bounds MUST stay (512,2): VGPR cap (measured 76, no spills);
// tighter caps (r7/r23) forced VGPR<=64 -> hundreds of MB of scratch.
// 8 waves: 4 wave-rows (64) x 2 wave-cols (32); MF=4, NF=2.
// STAGE1: act = silu(x@gateT)*(x@upT)*w -> bf16 (act_r routed / act_s shared)
// STAGE2: routed -> bf16 out_slot rows; shared -> fp32 out (once per (t,h))
template <bool STAGE1>
__global__ __launch_bounds__(512, 2) void moe_gemm(
    const unsigned short* __restrict__ Axr, const unsigned short* __restrict__ Axs,
    const float* __restrict__ B1r_, const float* __restrict__ B2r_,
    const float* __restrict__ B1s_, const float* __restrict__ B2s_,
    void* __restrict__ Dr, void* __restrict__ Ds,
    const int* __restrict__ slot_token, const float* __restrict__ slot_w,
    const int* __restrict__ cnt, const int* __restrict__ off_arr,
    const int* __restrict__ tiles, const int* __restrict__ nt, int T) {
    constexpr bool DUAL = STAGE1;
    int bid = blockIdx.x;
    if (bid >= nt[STAGE1 ? 0 : 1]) return;
    int tdesc = tiles[bid];
    int e = tdesc & 255, itile = (tdesc >> 8) & 255, mtile = tdesc >> 16;
    bool sh = (e == E_NUM);
    int count = sh ? T : cnt[e];
    int base = sh ? 0 : off_arr[e];
    const int K = STAGE1 ? H_DIM : (sh ? SHARED_I_DIM : I_DIM);

    __shared__ __align__(16) unsigned short As[2][256 * 32];    // 32 KB
    __shared__ __align__(16) unsigned short Bs1[2][64 * 32];    // 8 KB
    __shared__ __align__(16) unsigned short Bs2[2][DUAL ? 64 * 32 : 8];

    int tid = threadIdx.x, lane = tid & 63, wid = tid >> 6;

    // ---- A staging: 2 threads/row, 2x16B chunks each ----
    int as_row = tid >> 1, as_c0 = (tid & 1) * 2;
    int am = mtile * 256 + as_row;
    int amc = (am < count) ? am : 0;
    const unsigned short* Abase;
    size_t arow;
    if constexpr (STAGE1) {
        Abase = Axr;
        arow = sh ? (size_t)amc : (size_t)slot_token[base + amc];
    } else {
        Abase = sh ? Axs : Axr;
        arow = sh ? (size_t)amc : (size_t)(base + amc);
    }
    const unsigned short* Ga = Abase + arow * K + as_c0 * 8;

    // ---- B staging: 8 threads/row, 4 floats each -> 8B bf16 ds_write ----
    int bs_row = tid >> 3;
    int brow = itile * 64 + bs_row;
    int bwr = laddr(bs_row, (tid & 7) >> 1) + (tid & 1) * 4;
    const float* Gb1;
    const float* Gb2 = nullptr;
    if constexpr (STAGE1) {
        Gb1 = (sh ? B1s_ : (B1r_ + (size_t)e * (I_DIM * H_DIM))) + (size_t)brow * K + (tid & 7) * 4;
        Gb2 = (sh ? B2s_ : (B2r_ + (size_t)e * (I_DIM * H_DIM))) + (size_t)brow * K + (tid & 7) * 4;
    } else {
        Gb1 = (sh ? B1s_ : (B1r_ + (size_t)e * (H_DIM * I_DIM))) + (size_t)brow * K + (tid & 7) * 4;
    }

    f32x4 acc1[4][2] = {};
    f32x4 acc2[DUAL ? 4 : 1][2] = {};

    int wrow = (wid >> 1) * 64, wcol = (wid & 1) * 32;
    int frow = lane & 15, fch = lane >> 4;

    // 2-deep prefetch sets (all statically indexed)
    u16x8 a00, a01, a10, a11;
    float4 b10, b20, b11, b21;

    auto loadS = [&](u16x8& a0, u16x8& a1, float4& b1v, float4& b2v, int ks) {
        int k0 = ks << 5;
        a0 = *(const u16x8*)(Ga + k0);
        a1 = *(const u16x8*)(Ga + k0 + 8);
        b1v = *(const float4*)(Gb1 + k0);
        if constexpr (DUAL) b2v = *(const float4*)(Gb2 + k0);
    };
    auto writeS = [&](int buf, u16x8 a0, u16x8 a1, float4 b1v, float4 b2v) {
        *(u16x8*)(&As[buf][laddr(as_row, as_c0)]) = a0;
        *(u16x8*)(&As[buf][laddr(as_row, as_c0 + 1)]) = a1;
        ushort4 s;
        s.x = f2bf(b1v.x); s.y = f2bf(b1v.y); s.z = f2bf(b1v.z); s.w = f2bf(b1v.w);
        *(ushort4*)(&Bs1[buf][bwr]) = s;
        if constexpr (DUAL) {
            ushort4 s2;
            s2.x = f2bf(b2v.x); s2.y = f2bf(b2v.y); s2.z = f2bf(b2v.z); s2.w = f2bf(b2v.w);
            *(ushort4*)(&Bs2[buf][bwr]) = s2;
        }
    };
    auto compute = [&](int buf) {
        bf16x8 af[4], b1[2], b2[DUAL ? 2 : 1];
#pragma unroll
        for (int nf = 0; nf < 2; nf++)
            b1[nf] = *(const bf16x8*)(&Bs1[buf][laddr(wcol + nf * 16 + frow, fch)]);
        if constexpr (DUAL) {
#pragma unroll
            for (int nf = 0; nf < 2; nf++)
                b2[nf] = *(const bf16x8*)(&Bs2[buf][laddr(wcol + nf * 16 + frow, fch)]);
        }
#pragma unroll
        for (int mf = 0; mf < 4; mf++)
            af[mf] = *(const bf16x8*)(&As[buf][laddr(wrow + mf * 16 + frow, fch)]);
        __builtin_amdgcn_s_setprio(1);             // favor MFMA-phase waves
#pragma unroll
        for (int mf = 0; mf < 4; mf++)
#pragma unroll
            for (int nf = 0; nf < 2; nf++) {
                acc1[mf][nf] = __builtin_amdgcn_mfma_f32_16x16x32_bf16(af[mf], b1[nf], acc1[mf][nf], 0, 0, 0);
                if constexpr (DUAL)
                    acc2[mf][nf] = __builtin_amdgcn_mfma_f32_16x16x32_bf16(af[mf], b2[nf], acc2[mf][nf], 0, 0, 0);
            }
        __builtin_amdgcn_s_setprio(0);
    };

    const int NK = K >> 5;   // 32 or 16 (even)
    loadS(a00, a01, b10, b20, 0);
    loadS(a10, a11, b11, b21, 1);
    writeS(0, a00, a01, b10, b20);
    loadS(a00, a01, b10, b20, 2);
    __syncthreads();                               // buf0 ready
    for (int it = 0; it < NK; it += 2) {
        writeS(1, a10, a11, b11, b21);
        if (it + 3 < NK) loadS(a10, a11, b11, b21, it + 3);
        compute(0);
        __syncthreads();                           // buf1 ready, buf0 free
        if (it + 2 < NK) {
            writeS(0, a00, a01, b10, b20);
            if (it + 4 < NK) loadS(a00, a01, b10, b20, it + 4);
        }
        compute(1);
        if (it + 2 < NK) __syncthreads();          // buf0 ready, buf1 free
    }

    // ---- epilogue ----
#pragma unroll
    for (int mf = 0; mf < 4; mf++)
#pragma unroll
        for (int nf = 0; nf < 2; nf++)
#pragma unroll
            for (int j = 0; j < 4; j++) {
                int rloc = wrow + mf * 16 + (lane >> 4) * 4 + j;
                int mrow = mtile * 256 + rloc;
                int col = itile * 64 + wcol + nf * 16 + (lane & 15);
                if (mrow >= count) continue;
                if constexpr (STAGE1) {
                    float w = sh ? 1.0f : slot_w[base + mrow];
                    float g = acc1[mf][nf][j];
                    float a = (g / (1.f + __expf(-g))) * acc2[mf][nf][j] * w;
                    if (sh) ((unsigned short*)Ds)[(size_t)mrow * SHARED_I_DIM + col] = f2bf(a);
                    else    ((unsigned short*)Dr)[(size_t)(base + mrow) * I_DIM + col] = f2bf(a);
                } else {
                    if (sh) ((float*)Ds)[(size_t)mrow * H_DIM + col] = acc1[mf][nf][j];
                    else    ((unsigned short*)Dr)[(size_t)(base + mrow) * H_DIM + col] = f2bf(acc1[mf][nf][j]);
                }
            }
}

extern "C" void kernel_launch(void* const* d_in, const int* in_sizes, int n_in,
                              void* d_out, int out_size, void* d_ws, size_t ws_size,
                              hipStream_t stream) {
    const float* x = (const float*)d_in[0];
    const float* gw = (const float*)d_in[1];
    const float* gb = (const float*)d_in[2];
    const float* gate_proj = (const float*)d_in[3];
    const float* up_proj = (const float*)d_in[4];
    const float* down_proj = (const float*)d_in[5];
    const float* sgw = (const float*)d_in[6];
    const float* suw = (const float*)d_in[7];
    const float* sdw = (const float*)d_in[8];
    float* out = (float*)d_out;

    const int T = in_sizes[0] / H_DIM;       // 2048
    const int total_slots = T * TOPK;        // 8192

    char* ws = (char*)d_ws;
    int* cnt = (int*)ws;                     // 32
    int* cnt2 = cnt + 32;                    // 32
    int* off = cnt + 64;                     // 33
    int* nt = cnt + 100;                     // 2
    int* tiles1 = cnt + 128;                 // <= 768
    int* tiles2 = tiles1 + 768;              // <= 1280
    int* topk_e = tiles2 + 1280;
    float* topk_w = (float*)(topk_e + total_slots);
    int* slot_token = (int*)(topk_w + total_slots);
    float* slot_w = (float*)(slot_token + total_slots);
    int* slot_of = (int*)(slot_w + total_slots);
    float* logits = (float*)(slot_of + total_slots);              // T*32 f32
    unsigned short* x_bf = (unsigned short*)(logits + (size_t)T * E_NUM);
    unsigned short* act_r = x_bf + (size_t)T * H_DIM;             // (slots+256) x I
    unsigned short* act_s = act_r + (size_t)(total_slots + 256) * I_DIM;   // T x SHARED_I
    unsigned short* out_slot = act_s + (size_t)T * SHARED_I_DIM;  // (slots+256) x H

    // gate: logits + bf16 copy of x + zeroing of cnt/cnt2 (block 0)
    hipLaunchKernelGGL(gate_kernel, dim3(T / GT), dim3(256), 0, stream,
                       x, gw, logits, x_bf, cnt);
    hipLaunchKernelGGL(select_kernel, dim3((T + 255) / 256), dim3(256), 0, stream,
                       logits, gb, topk_e, topk_w, cnt, T);
    hipLaunchKernelGGL(scan_kernel, dim3(1), dim3(256), 0, stream,
                       cnt, off, tiles1, tiles2, nt, T);
    hipLaunchKernelGGL(bin_kernel, dim3((total_slots + 255) / 256), dim3(256), 0, stream,
                       topk_e, topk_w, off, cnt2, slot_token, slot_w, slot_of, total_slots);

    // stage 1 (compact 1-D grid; live tiles contiguous from block 0)
    hipLaunchKernelGGL((moe_gemm<true>), dim3(768), dim3(512), 0, stream,
                       x_bf, (const unsigned short*)nullptr,
                       gate_proj, up_proj, sgw, suw,
                       (void*)act_r, (void*)act_s,
                       slot_token, slot_w, cnt, off, tiles1, nt, T);

    // stage 2 (compact 1-D grid)
    hipLaunchKernelGGL((moe_gemm<false>), dim3(1280), dim3(512), 0, stream,
                       act_r, act_s,
                       down_proj, (const float*)nullptr, sdw, (const float*)nullptr,
                       (void*)out_slot, (void*)out,
                       slot_token, slot_w, cnt, off, tiles2, nt, T);

    // combine: out[t] += sum of the token's 4 routed slot rows
    hipLaunchKernelGGL(combine_kernel, dim3(T), dim3(256), 0, stream, out_slot, slot_of, out);
}